// Round 6
// baseline (678.262 us; speedup 1.0000x reference)
//
#include <hip/hip_runtime.h>
#include <math.h>

// ---------------- problem constants ----------------
#define NB     8
#define NT     1000
#define NMEL   80
#define NFREQ  513      // 1024/2+1
#define NFFT   1024
#define WINL   1024
#define HOP    256
#define SIGL   256768   // (NT-1)*HOP + WINL
#define NFRM   8000     // NB*NT
#define NITER  8

// padded LDS indexing for FFT buffers
#define IDX(x) ((x) + ((x) >> 6))
#define LDS512 520      // IDX(511)=518 max

// ---------------- workspace layout (bytes) ----------------
#define OFF_G      ((size_t)0)                       // double G[80][80]
#define SZ_G       ((size_t)NMEL*NMEL*8)
#define OFF_GINV   (OFF_G + SZ_G)
#define SZ_GINV    ((size_t)NMEL*NMEL*8)
#define OFF_INVMEL (OFF_GINV + SZ_GINV)              // float invmelT[80][513]
#define SZ_INVMEL  ((size_t)NFREQ*NMEL*4)
#define OFF_WINF   (OFF_INVMEL + SZ_INVMEL)          // float winf[1024]
#define OFF_WINS   (OFF_WINF + 4096)                 // float wins[1024]
#define OFF_MAG    (OFF_WINS + 4096)                 // float mag[8000][513]
#define SZ_MAG     ((size_t)NFRM*NFREQ*4)
#define OFF_PH     (OFF_MAG + SZ_MAG)                // float2 phase[8000][513]
#define SZ_PH      ((size_t)NFRM*NFREQ*8)
#define OFF_FR     (OFF_PH + SZ_PH)                  // float frames[8000][1024]
#define SZ_FR      ((size_t)NFRM*NFFT*4)
#define OFF_SIG    (OFF_FR + SZ_FR)                  // float sig[8][256768]
#define SZ_SIG     ((size_t)NB*SIGL*4)

// ---------------- small precompute kernels ----------------

__global__ void k_windows(float* __restrict__ winf, float* __restrict__ wins) {
    int t = threadIdx.x; // 256 threads
    for (int n = t; n < WINL; n += 256) {
        double w = 0.5 - 0.5 * cos(2.0 * M_PI * (double)n / (double)WINL);
        winf[n] = (float)w;
    }
    __syncthreads();
    {
        float a0 = winf[t], a1 = winf[t + 256], a2 = winf[t + 512], a3 = winf[t + 768];
        float den = a0 * a0;
        den += a1 * a1; den += a2 * a2; den += a3 * a3;
        wins[t]       = a0 / den;
        wins[t + 256] = a1 / den;
        wins[t + 512] = a2 / den;
        wins[t + 768] = a3 / den;
    }
}

// G = B B^T (f64)
__global__ void k_gram(const float* __restrict__ Bm, double* __restrict__ G) {
    int i = blockIdx.x; // 80 blocks
    for (int j = threadIdx.x; j < NMEL; j += blockDim.x) {
        double s = 0.0;
        for (int f = 0; f < NFREQ; ++f)
            s += (double)Bm[i * NFREQ + f] * (double)Bm[j * NFREQ + f];
        G[i * NMEL + j] = s;
    }
}

// Register-tiled in-place Gauss-Jordan inversion of SPD 80x80 (proven round 3).
__global__ __launch_bounds__(256) void k_gjinv(const double* __restrict__ G,
                                               double* __restrict__ Ginv) {
    __shared__ double fcol[2][NMEL];
    __shared__ double prow[2][NMEL];
    __shared__ double App[2];
    double A[5][5];
    const int t = threadIdx.x, tx = t & 15, ty = t >> 4;
    const int R0 = ty * 5, C0 = tx * 5;
#pragma unroll
    for (int r = 0; r < 5; ++r)
#pragma unroll
        for (int c = 0; c < 5; ++c)
            A[r][c] = G[(R0 + r) * NMEL + C0 + c];
    __syncthreads();
#pragma unroll
    for (int p = 0; p < NMEL; ++p) {
        const int pb = p / 5, pi = p % 5;
        const int cur = p & 1;
        if (tx == pb) {
#pragma unroll
            for (int r = 0; r < 5; ++r) fcol[cur][R0 + r] = A[r][pi];
            if (ty == pb) App[cur] = A[pi][pi];
        }
        __syncthreads();
        const double d = 1.0 / App[cur];
        if (ty == pb) {
#pragma unroll
            for (int c = 0; c < 5; ++c) {
                double v = (tx == pb && c == pi) ? d : A[pi][c] * d;
                A[pi][c] = v;
                prow[cur][C0 + c] = v;
            }
        }
        __syncthreads();
        double fr[5], pc[5];
#pragma unroll
        for (int r = 0; r < 5; ++r) fr[r] = fcol[cur][R0 + r];
#pragma unroll
        for (int c = 0; c < 5; ++c) pc[c] = prow[cur][C0 + c];
#pragma unroll
        for (int r = 0; r < 5; ++r) {
            const bool isPivRow = (ty == pb) && (r == pi);
            if (!isPivRow) {
#pragma unroll
                for (int c = 0; c < 5; ++c) {
                    const bool isPivCol = (tx == pb) && (c == pi);
                    A[r][c] = isPivCol ? (-fr[r] * d) : fma(-fr[r], pc[c], A[r][c]);
                }
            }
        }
    }
#pragma unroll
    for (int r = 0; r < 5; ++r)
#pragma unroll
        for (int c = 0; c < 5; ++c)
            Ginv[(R0 + r) * NMEL + C0 + c] = A[r][c];
}

// invmelT[m][f] = sum_k B[k][f] * Ginv[k][m]   (TRANSPOSED output)
__global__ void k_invmel(const float* __restrict__ Bm, const double* __restrict__ Ginv,
                         float* __restrict__ ivT) {
    int idx = blockIdx.x * blockDim.x + threadIdx.x;
    if (idx >= NFREQ * NMEL) return;
    int f = idx / NMEL, m = idx - f * NMEL;
    double s = 0.0;
    for (int k = 0; k < NMEL; ++k)
        s += (double)Bm[k * NFREQ + f] * Ginv[k * NMEL + m];
    ivT[m * NFREQ + f] = (float)s;
}

// mag: fused melpow (10^(mel*scale+mean)) + 8 bt-rows per block GEMM-ish
#define MAGROWS 8
__global__ __launch_bounds__(256) void k_mag(const float* __restrict__ mel,
                                             const float* __restrict__ smean,
                                             const float* __restrict__ sscale,
                                             const float* __restrict__ ivT,
                                             float* __restrict__ mag) {
    __shared__ float rows[MAGROWS][NMEL];
    int bt0 = blockIdx.x * MAGROWS;
    for (int e = threadIdx.x; e < MAGROWS * NMEL; e += 256) {
        int m = e % NMEL;
        rows[e / NMEL][m] = exp10f(mel[(size_t)bt0 * NMEL + e] * sscale[m] + smean[m]);
    }
    __syncthreads();
    for (int f = threadIdx.x; f < NFREQ; f += 256) {
        float acc[MAGROWS];
#pragma unroll
        for (int r = 0; r < MAGROWS; ++r) acc[r] = 0.f;
        for (int m = 0; m < NMEL; ++m) {
            float iv = ivT[m * NFREQ + f];
#pragma unroll
            for (int r = 0; r < MAGROWS; ++r) acc[r] = fmaf(rows[r][m], iv, acc[r]);
        }
#pragma unroll
        for (int r = 0; r < MAGROWS; ++r)
            mag[(size_t)(bt0 + r) * NFREQ + f] = fmaxf(1e-10f, acc[r]);
    }
}

// ---------------- threefry2x32 (JAX-exact, partitionable mode) ----------------
__device__ inline unsigned rotl32(unsigned x, int d) { return (x << d) | (x >> (32 - d)); }

__device__ inline void threefry2x32(unsigned k0, unsigned k1, unsigned& x0, unsigned& x1) {
    unsigned ks0 = k0, ks1 = k1, ks2 = k0 ^ k1 ^ 0x1BD11BDAu;
    x0 += ks0; x1 += ks1;
#define TFR(r) { x0 += x1; x1 = rotl32(x1, r); x1 ^= x0; }
    TFR(13) TFR(15) TFR(26) TFR(6)   x0 += ks1; x1 += ks2 + 1u;
    TFR(17) TFR(29) TFR(16) TFR(24)  x0 += ks2; x1 += ks0 + 2u;
    TFR(13) TFR(15) TFR(26) TFR(6)   x0 += ks0; x1 += ks1 + 3u;
    TFR(17) TFR(29) TFR(16) TFR(24)  x0 += ks1; x1 += ks2 + 4u;
    TFR(13) TFR(15) TFR(26) TFR(6)   x0 += ks2; x1 += ks0 + 5u;
#undef TFR
}

__device__ inline float bits_to_unit(unsigned bits) {
    return __uint_as_float((bits >> 9) | 0x3F800000u) - 1.0f;
}

__device__ inline float2 rand_phase(int i) {
    unsigned x0 = 0u, x1 = (unsigned)i;
    threefry2x32(0u, 1u, x0, x1);
    float u = bits_to_unit(x0 ^ x1);
    float ang = 6.283185307179586f * u;
    return make_float2(cosf(ang), sinf(ang));
}

// ---------------- register twiddles ----------------
// Stage-s radix-4 twiddle angle is a per-lane constant: -2*pi*(w & ~((1<<2s)-1))/512.
__device__ inline void make_twr(int w, float2 twr[4][3]) {
#pragma unroll
    for (int s = 0; s < 4; ++s) {
        const int msk = (1 << (2 * s)) - 1;
        const float ang = -6.2831853071795864769f * (float)(w & ~msk) * (1.0f / 512.0f);
#pragma unroll
        for (int kk = 1; kk <= 3; ++kk) {
            float sv, cv;
            sincosf(ang * (float)kk, &sv, &cv);
            twr[s][kk - 1] = make_float2(cv, sv);
        }
    }
}

// ppr[j] = e^{-2*pi*i*(w+128j)/1024}
__device__ inline void make_ppr(int w, float2 ppr[4]) {
#pragma unroll
    for (int j = 0; j < 4; ++j) {
        float sv, cv;
        sincosf(-6.2831853071795864769f * (float)(w + 128 * j) * (1.0f / 1024.0f), &sv, &cv);
        ppr[j] = make_float2(cv, sv);
    }
}

// ---------------- 512-pt complex FFT (radix-4 x4 + radix-2), 128 lanes/frame ----
template <bool INV>
__device__ inline float2* fft512(float2* a, float2* b, const float2 twr[4][3],
                                 const int w) {
#pragma unroll
    for (int s = 0; s < 4; ++s) {
        const int slog = 2 * s;
        const int q = w & ((1 << slog) - 1);
        const int p = w >> slog;
        float2 x0 = a[IDX(w)];
        float2 x1 = a[IDX(w + 128)];
        float2 x2 = a[IDX(w + 256)];
        float2 x3 = a[IDX(w + 384)];
        float2 t0 = make_float2(x0.x + x2.x, x0.y + x2.y);
        float2 t1 = make_float2(x0.x - x2.x, x0.y - x2.y);
        float2 t2 = make_float2(x1.x + x3.x, x1.y + x3.y);
        float2 tm = make_float2(x1.x - x3.x, x1.y - x3.y);
        float2 it3 = INV ? make_float2(-tm.y, tm.x) : make_float2(tm.y, -tm.x);
        float2 y0 = make_float2(t0.x + t2.x, t0.y + t2.y);
        float2 u1 = make_float2(t1.x + it3.x, t1.y + it3.y);
        float2 u2 = make_float2(t0.x - t2.x, t0.y - t2.y);
        float2 u3 = make_float2(t1.x - it3.x, t1.y - it3.y);
        float2 w1 = twr[s][0], w2 = twr[s][1], w3 = twr[s][2];
        float s1 = INV ? -w1.y : w1.y;
        float s2 = INV ? -w2.y : w2.y;
        float s3 = INV ? -w3.y : w3.y;
        float2 y1 = make_float2(u1.x * w1.x - u1.y * s1, u1.x * s1 + u1.y * w1.x);
        float2 y2 = make_float2(u2.x * w2.x - u2.y * s2, u2.x * s2 + u2.y * w2.x);
        float2 y3 = make_float2(u3.x * w3.x - u3.y * s3, u3.x * s3 + u3.y * w3.x);
        const int wb = q + (p << (slog + 2));
        b[IDX(wb)]               = y0;
        b[IDX(wb + (1 << slog))] = y1;
        b[IDX(wb + (2 << slog))] = y2;
        b[IDX(wb + (3 << slog))] = y3;
        __syncthreads();
        float2* tsw = a; a = b; b = tsw;
    }
    // final radix-2 (twiddle-free), 2 butterflies/lane
#pragma unroll
    for (int r = 0; r < 2; ++r) {
        const int bb = w + 128 * r;
        float2 x0 = a[IDX(bb)];
        float2 x1 = a[IDX(bb + 256)];
        b[IDX(bb)]       = make_float2(x0.x + x1.x, x0.y + x1.y);
        b[IDX(bb + 256)] = make_float2(x0.x - x1.x, x0.y - x1.y);
    }
    __syncthreads();
    return b;
}

// ISTFT: X=mag*phase -> pack Z=Xe+i*Xo -> IFFT512 -> x[2n]=Re, x[2n+1]=Im -> *syn
// Two frames per block. FIRST: inline threefry random phase (fuses phase-init).
template <bool FIRST>
__global__ __launch_bounds__(256) void k_istft(const float* __restrict__ mag,
                                               const float2* __restrict__ phase,
                                               const float* __restrict__ wins,
                                               float* __restrict__ frames) {
    __shared__ float2 A[2][LDS512];
    __shared__ float2 B[2][LDS512];
    const int t = threadIdx.x, sub = t >> 7, w = t & 127;
    const int bt = blockIdx.x * 2 + sub;
    float2 twr[4][3], ppr[4];
    make_twr(w, twr);
    make_ppr(w, ppr);
    const float*  mg = mag   + (size_t)bt * NFREQ;
    const float2* ph = phase + (size_t)bt * NFREQ;
    auto loadX = [&](int k) -> float2 {
        float m = mg[k];
        float2 p;
        if (FIRST) p = rand_phase(bt * NFREQ + k);
        else       p = ph[k];
        float2 X = make_float2(m * p.x, m * p.y);
        if (k == 0 || k == 512) X.y = 0.f;   // C2R drops imag of DC/Nyquist
        return X;
    };
#pragma unroll
    for (int j = 0; j < 4; ++j) {
        int k = w + 128 * j;
        float2 Xk = loadX(k);
        float2 Xc = loadX(512 - k);
        float ex = 0.5f * (Xk.x + Xc.x), ey = 0.5f * (Xk.y - Xc.y);
        float dx = 0.5f * (Xk.x - Xc.x), dy = 0.5f * (Xk.y + Xc.y);
        float2 c = ppr[j];                        // e^{-i th}; W^{-k} = conj(c)
        float ox = c.x * dx + c.y * dy;
        float oy = c.x * dy - c.y * dx;
        A[sub][IDX(k)] = make_float2(ex - oy, ey + ox);   // Z = Xe + i Xo
    }
    __syncthreads();
    float2* res = fft512<true>(&A[sub][0], &B[sub][0], twr, w);
    float2* out2 = (float2*)(frames + (size_t)bt * NFFT);
    const float2* wn2 = (const float2*)wins;
    const float inv = 1.0f / 512.0f;
#pragma unroll
    for (int j = 0; j < 4; ++j) {
        int n = w + 128 * j;
        float2 z = res[IDX(n)];
        float2 wv = wn2[n];
        out2[n] = make_float2(z.x * inv * wv.x, z.y * inv * wv.y);
    }
}

// STFT: z[n]=x[2n]w+i x[2n+1]w -> FFT512 -> unpack X[k] -> phase normalize
__global__ __launch_bounds__(256) void k_stft(const float* __restrict__ sig,
                                              const float* __restrict__ winf,
                                              float2* __restrict__ phase) {
    __shared__ float2 A[2][LDS512];
    __shared__ float2 B[2][LDS512];
    const int t = threadIdx.x, sub = t >> 7, w = t & 127;
    const int bt = blockIdx.x * 2 + sub;
    const int b = bt / NT, tt = bt - b * NT;
    const float2* x2 = (const float2*)(sig + (size_t)b * SIGL + (size_t)tt * HOP);
    const float2* wf2 = (const float2*)winf;
    float2 twr[4][3], ppr[4];
    make_twr(w, twr);
    make_ppr(w, ppr);
#pragma unroll
    for (int j = 0; j < 4; ++j) {
        int n = w + 128 * j;
        float2 v = x2[n];
        float2 wv = wf2[n];
        A[sub][IDX(n)] = make_float2(v.x * wv.x, v.y * wv.y);
    }
    __syncthreads();
    float2* res = fft512<false>(&A[sub][0], &B[sub][0], twr, w);
    float2* out = phase + (size_t)bt * NFREQ;
#pragma unroll
    for (int j = 0; j < 5; ++j) {
        int k = w + 128 * j;
        if (k > 512) break;
        float2 X;
        if (k == 0 || k == 512) {
            float2 z0 = res[IDX(0)];
            X = make_float2((k == 0) ? (z0.x + z0.y) : (z0.x - z0.y), 0.f);
        } else {
            float2 Zk = res[IDX(k)];
            float2 Zc = res[IDX(512 - k)];
            float ex = 0.5f * (Zk.x + Zc.x), ey = 0.5f * (Zk.y - Zc.y);
            float dx = 0.5f * (Zk.x - Zc.x), dy = 0.5f * (Zk.y + Zc.y);
            float ox = dy, oy = -dx;              // O = -i*d
            float2 c = ppr[j];                     // W^{+k} in e^{-i} convention
            X = make_float2(ex + c.x * ox - c.y * oy, ey + c.x * oy + c.y * ox);
        }
        float aab = sqrtf(X.x * X.x + X.y * X.y);
        float iv = 1.0f / fmaxf(1e-10f, aab);
        out[k] = make_float2(X.x * iv, X.y * iv);
    }
}

// overlap-add (gather): sig[b][l] = sum_t frames[b*NT+t][l-256t]
__global__ void k_ola(const float* __restrict__ frames, float* __restrict__ sig) {
    int idx = blockIdx.x * blockDim.x + threadIdx.x;
    if (idx >= NB * SIGL) return;
    int b = idx / SIGL, l = idx - b * SIGL;
    int tmax = min(NT - 1, l >> 8);
    int tmin = (l >= WINL) ? ((l - (WINL - HOP)) >> 8) : 0;
    float s = 0.f;
    for (int t = tmin; t <= tmax; ++t)
        s += frames[((size_t)(b * NT + t)) * NFFT + (l - (t << 8))];
    sig[idx] = s;
}

// ---------------- launcher ----------------
extern "C" void kernel_launch(void* const* d_in, const int* in_sizes, int n_in,
                              void* d_out, int out_size, void* d_ws, size_t ws_size,
                              hipStream_t stream) {
    const float* mel    = (const float*)d_in[0];
    const float* basis  = (const float*)d_in[1];
    const float* smean  = (const float*)d_in[2];
    const float* sscale = (const float*)d_in[3];

    char* ws = (char*)d_ws;
    double* G      = (double*)(ws + OFF_G);
    double* Ginv   = (double*)(ws + OFF_GINV);
    float*  ivT    = (float*) (ws + OFF_INVMEL);
    float*  winf   = (float*) (ws + OFF_WINF);
    float*  wins   = (float*) (ws + OFF_WINS);
    float*  mag    = (float*) (ws + OFF_MAG);
    float2* phase  = (float2*)(ws + OFF_PH);
    float*  frames = (float*) (ws + OFF_FR);
    float*  sig    = (float*) (ws + OFF_SIG);
    float*  outp   = (float*)d_out;

    k_windows<<<1, 256, 0, stream>>>(winf, wins);
    k_gram<<<80, 256, 0, stream>>>(basis, G);
    k_gjinv<<<1, 256, 0, stream>>>(G, Ginv);
    k_invmel<<<(NFREQ * NMEL + 255) / 256, 256, 0, stream>>>(basis, Ginv, ivT);
    k_mag<<<NFRM / MAGROWS, 256, 0, stream>>>(mel, smean, sscale, ivT, mag);

    // iteration 0: phase-init fused into first ISTFT
    k_istft<true><<<NFRM / 2, 256, 0, stream>>>(mag, phase, wins, frames);
    k_ola<<<(NB * SIGL + 255) / 256, 256, 0, stream>>>(frames, sig);
    k_stft<<<NFRM / 2, 256, 0, stream>>>(sig, winf, phase);
    for (int it = 1; it < NITER; ++it) {
        k_istft<false><<<NFRM / 2, 256, 0, stream>>>(mag, phase, wins, frames);
        k_ola<<<(NB * SIGL + 255) / 256, 256, 0, stream>>>(frames, sig);
        k_stft<<<NFRM / 2, 256, 0, stream>>>(sig, winf, phase);
    }
    k_istft<false><<<NFRM / 2, 256, 0, stream>>>(mag, phase, wins, frames);
    k_ola<<<(NB * SIGL + 255) / 256, 256, 0, stream>>>(frames, outp);
}

// Round 7
// 566.767 us; speedup vs baseline: 1.1967x; 1.1967x over previous
//
#include <hip/hip_runtime.h>
#include <math.h>

// ---------------- problem constants ----------------
#define NB     8
#define NT     1000
#define NMEL   80
#define NFREQ  513      // 1024/2+1
#define NFFT   1024
#define WINL   1024
#define HOP    256
#define SIGL   256768   // (NT-1)*HOP + WINL
#define NFRM   8000     // NB*NT
#define NITER  8

// padded LDS indexing for FFT buffers
#define IDX(x) ((x) + ((x) >> 6))
#define LDS512 520      // IDX(511)=518 max

// ---------------- workspace layout (bytes) ----------------
#define OFF_G      ((size_t)0)                       // double G[80][80]
#define SZ_G       ((size_t)NMEL*NMEL*8)
#define OFF_GINV   (OFF_G + SZ_G)
#define SZ_GINV    ((size_t)NMEL*NMEL*8)
#define OFF_INVMEL (OFF_GINV + SZ_GINV)              // float invmelT[80][513]
#define SZ_INVMEL  ((size_t)NFREQ*NMEL*4)
#define OFF_WINF   (OFF_INVMEL + SZ_INVMEL)          // float winf[1024]
#define OFF_WINS   (OFF_WINF + 4096)                 // float wins[1024] (pre-scaled /512)
#define OFF_MAG    (OFF_WINS + 4096)                 // float mag[8000][513]
#define SZ_MAG     ((size_t)NFRM*NFREQ*4)
#define OFF_PH     (OFF_MAG + SZ_MAG)                // float2 phase[8000][513]
#define SZ_PH      ((size_t)NFRM*NFREQ*8)
#define OFF_FR     (OFF_PH + SZ_PH)                  // float frames[8000][1024]
#define SZ_FR      ((size_t)NFRM*NFFT*4)
#define OFF_SIG    (OFF_FR + SZ_FR)                  // float sig[8][256768]
#define SZ_SIG     ((size_t)NB*SIGL*4)

// ---------------- small precompute kernels ----------------

__global__ void k_windows(float* __restrict__ winf, float* __restrict__ wins) {
    int t = threadIdx.x; // 256 threads
    for (int n = t; n < WINL; n += 256) {
        double w = 0.5 - 0.5 * cos(2.0 * M_PI * (double)n / (double)WINL);
        winf[n] = (float)w;
    }
    __syncthreads();
    {
        float a0 = winf[t], a1 = winf[t + 256], a2 = winf[t + 512], a3 = winf[t + 768];
        float den = a0 * a0;
        den += a1 * a1; den += a2 * a2; den += a3 * a3;
        // fold the 1/512 IFFT normalization into the synthesis window
        const float s = 1.0f / 512.0f;
        wins[t]       = a0 / den * s;
        wins[t + 256] = a1 / den * s;
        wins[t + 512] = a2 / den * s;
        wins[t + 768] = a3 / den * s;
    }
}

// G = B B^T (f64)
__global__ void k_gram(const float* __restrict__ Bm, double* __restrict__ G) {
    int i = blockIdx.x; // 80 blocks
    for (int j = threadIdx.x; j < NMEL; j += blockDim.x) {
        double s = 0.0;
        for (int f = 0; f < NFREQ; ++f)
            s += (double)Bm[i * NFREQ + f] * (double)Bm[j * NFREQ + f];
        G[i * NMEL + j] = s;
    }
}

// Register-tiled in-place Gauss-Jordan inversion of SPD 80x80 (proven round 3).
__global__ __launch_bounds__(256) void k_gjinv(const double* __restrict__ G,
                                               double* __restrict__ Ginv) {
    __shared__ double fcol[2][NMEL];
    __shared__ double prow[2][NMEL];
    __shared__ double App[2];
    double A[5][5];
    const int t = threadIdx.x, tx = t & 15, ty = t >> 4;
    const int R0 = ty * 5, C0 = tx * 5;
#pragma unroll
    for (int r = 0; r < 5; ++r)
#pragma unroll
        for (int c = 0; c < 5; ++c)
            A[r][c] = G[(R0 + r) * NMEL + C0 + c];
    __syncthreads();
#pragma unroll
    for (int p = 0; p < NMEL; ++p) {
        const int pb = p / 5, pi = p % 5;
        const int cur = p & 1;
        if (tx == pb) {
#pragma unroll
            for (int r = 0; r < 5; ++r) fcol[cur][R0 + r] = A[r][pi];
            if (ty == pb) App[cur] = A[pi][pi];
        }
        __syncthreads();
        const double d = 1.0 / App[cur];
        if (ty == pb) {
#pragma unroll
            for (int c = 0; c < 5; ++c) {
                double v = (tx == pb && c == pi) ? d : A[pi][c] * d;
                A[pi][c] = v;
                prow[cur][C0 + c] = v;
            }
        }
        __syncthreads();
        double fr[5], pc[5];
#pragma unroll
        for (int r = 0; r < 5; ++r) fr[r] = fcol[cur][R0 + r];
#pragma unroll
        for (int c = 0; c < 5; ++c) pc[c] = prow[cur][C0 + c];
#pragma unroll
        for (int r = 0; r < 5; ++r) {
            const bool isPivRow = (ty == pb) && (r == pi);
            if (!isPivRow) {
#pragma unroll
                for (int c = 0; c < 5; ++c) {
                    const bool isPivCol = (tx == pb) && (c == pi);
                    A[r][c] = isPivCol ? (-fr[r] * d) : fma(-fr[r], pc[c], A[r][c]);
                }
            }
        }
    }
#pragma unroll
    for (int r = 0; r < 5; ++r)
#pragma unroll
        for (int c = 0; c < 5; ++c)
            Ginv[(R0 + r) * NMEL + C0 + c] = A[r][c];
}

// invmelT[m][f] = sum_k B[k][f] * Ginv[k][m]   (TRANSPOSED output)
__global__ void k_invmel(const float* __restrict__ Bm, const double* __restrict__ Ginv,
                         float* __restrict__ ivT) {
    int idx = blockIdx.x * blockDim.x + threadIdx.x;
    if (idx >= NFREQ * NMEL) return;
    int f = idx / NMEL, m = idx - f * NMEL;
    double s = 0.0;
    for (int k = 0; k < NMEL; ++k)
        s += (double)Bm[k * NFREQ + f] * Ginv[k * NMEL + m];
    ivT[m * NFREQ + f] = (float)s;
}

// mag: fused melpow (10^(mel*scale+mean)) + 8 bt-rows per block GEMM-ish
#define MAGROWS 8
__global__ __launch_bounds__(256) void k_mag(const float* __restrict__ mel,
                                             const float* __restrict__ smean,
                                             const float* __restrict__ sscale,
                                             const float* __restrict__ ivT,
                                             float* __restrict__ mag) {
    __shared__ float rows[MAGROWS][NMEL];
    int bt0 = blockIdx.x * MAGROWS;
    for (int e = threadIdx.x; e < MAGROWS * NMEL; e += 256) {
        int m = e % NMEL;
        rows[e / NMEL][m] = exp10f(mel[(size_t)bt0 * NMEL + e] * sscale[m] + smean[m]);
    }
    __syncthreads();
    for (int f = threadIdx.x; f < NFREQ; f += 256) {
        float acc[MAGROWS];
#pragma unroll
        for (int r = 0; r < MAGROWS; ++r) acc[r] = 0.f;
        for (int m = 0; m < NMEL; ++m) {
            float iv = ivT[m * NFREQ + f];
#pragma unroll
            for (int r = 0; r < MAGROWS; ++r) acc[r] = fmaf(rows[r][m], iv, acc[r]);
        }
#pragma unroll
        for (int r = 0; r < MAGROWS; ++r)
            mag[(size_t)(bt0 + r) * NFREQ + f] = fmaxf(1e-10f, acc[r]);
    }
}

// ---------------- threefry2x32 (JAX-exact, partitionable mode) ----------------
__device__ inline unsigned rotl32(unsigned x, int d) { return (x << d) | (x >> (32 - d)); }

__device__ inline void threefry2x32(unsigned k0, unsigned k1, unsigned& x0, unsigned& x1) {
    unsigned ks0 = k0, ks1 = k1, ks2 = k0 ^ k1 ^ 0x1BD11BDAu;
    x0 += ks0; x1 += ks1;
#define TFR(r) { x0 += x1; x1 = rotl32(x1, r); x1 ^= x0; }
    TFR(13) TFR(15) TFR(26) TFR(6)   x0 += ks1; x1 += ks2 + 1u;
    TFR(17) TFR(29) TFR(16) TFR(24)  x0 += ks2; x1 += ks0 + 2u;
    TFR(13) TFR(15) TFR(26) TFR(6)   x0 += ks0; x1 += ks1 + 3u;
    TFR(17) TFR(29) TFR(16) TFR(24)  x0 += ks1; x1 += ks2 + 4u;
    TFR(13) TFR(15) TFR(26) TFR(6)   x0 += ks2; x1 += ks0 + 5u;
#undef TFR
}

__device__ inline float bits_to_unit(unsigned bits) {
    return __uint_as_float((bits >> 9) | 0x3F800000u) - 1.0f;
}

// precise libm trig here: runs once, feeds the whole pipeline
__device__ inline float2 rand_phase(int i) {
    unsigned x0 = 0u, x1 = (unsigned)i;
    threefry2x32(0u, 1u, x0, x1);
    float u = bits_to_unit(x0 ^ x1);
    float ang = 6.283185307179586f * u;
    return make_float2(cosf(ang), sinf(ang));
}

// ---------------- register twiddles via HW trig (input in REVOLUTIONS) --------
// All twiddle angles are exact dyadic fractions -> rev is exact in f32; v_sin/v_cos
// then give ~1-ulp results with no libm range-reduction cost.
__device__ inline float2 cs_rev(float rev) {
    float r = rev - floorf(rev);   // v_fract; hw trig wants reduced input
    return make_float2(__builtin_amdgcn_cosf(r), __builtin_amdgcn_sinf(r));
}

// Stage-s radix-4 twiddle angle is a per-lane constant: -2*pi*(w & ~((1<<2s)-1))/512.
__device__ inline void make_twr(int w, float2 twr[4][3]) {
#pragma unroll
    for (int s = 0; s < 4; ++s) {
        const int msk = (1 << (2 * s)) - 1;
        const int base = w & ~msk;
#pragma unroll
        for (int kk = 1; kk <= 3; ++kk)
            twr[s][kk - 1] = cs_rev(-(float)(base * kk) * (1.0f / 512.0f));
    }
}

// ppr[j] = e^{-2*pi*i*(w+128j)/1024}
__device__ inline void make_ppr(int w, float2 ppr[4]) {
#pragma unroll
    for (int j = 0; j < 4; ++j)
        ppr[j] = cs_rev(-(float)(w + 128 * j) * (1.0f / 1024.0f));
}

// ---------------- 512-pt complex FFT (radix-4 x4 + radix-2), 128 lanes/frame ----
template <bool INV>
__device__ inline float2* fft512(float2* a, float2* b, const float2 twr[4][3],
                                 const int w) {
#pragma unroll
    for (int s = 0; s < 4; ++s) {
        const int slog = 2 * s;
        const int q = w & ((1 << slog) - 1);
        const int p = w >> slog;
        float2 x0 = a[IDX(w)];
        float2 x1 = a[IDX(w + 128)];
        float2 x2 = a[IDX(w + 256)];
        float2 x3 = a[IDX(w + 384)];
        float2 t0 = make_float2(x0.x + x2.x, x0.y + x2.y);
        float2 t1 = make_float2(x0.x - x2.x, x0.y - x2.y);
        float2 t2 = make_float2(x1.x + x3.x, x1.y + x3.y);
        float2 tm = make_float2(x1.x - x3.x, x1.y - x3.y);
        float2 it3 = INV ? make_float2(-tm.y, tm.x) : make_float2(tm.y, -tm.x);
        float2 y0 = make_float2(t0.x + t2.x, t0.y + t2.y);
        float2 u1 = make_float2(t1.x + it3.x, t1.y + it3.y);
        float2 u2 = make_float2(t0.x - t2.x, t0.y - t2.y);
        float2 u3 = make_float2(t1.x - it3.x, t1.y - it3.y);
        float2 w1 = twr[s][0], w2 = twr[s][1], w3 = twr[s][2];
        float s1 = INV ? -w1.y : w1.y;
        float s2 = INV ? -w2.y : w2.y;
        float s3 = INV ? -w3.y : w3.y;
        float2 y1 = make_float2(u1.x * w1.x - u1.y * s1, u1.x * s1 + u1.y * w1.x);
        float2 y2 = make_float2(u2.x * w2.x - u2.y * s2, u2.x * s2 + u2.y * w2.x);
        float2 y3 = make_float2(u3.x * w3.x - u3.y * s3, u3.x * s3 + u3.y * w3.x);
        const int wb = q + (p << (slog + 2));
        b[IDX(wb)]               = y0;
        b[IDX(wb + (1 << slog))] = y1;
        b[IDX(wb + (2 << slog))] = y2;
        b[IDX(wb + (3 << slog))] = y3;
        __syncthreads();
        float2* tsw = a; a = b; b = tsw;
    }
    // final radix-2 (twiddle-free), 2 butterflies/lane
#pragma unroll
    for (int r = 0; r < 2; ++r) {
        const int bb = w + 128 * r;
        float2 x0 = a[IDX(bb)];
        float2 x1 = a[IDX(bb + 256)];
        b[IDX(bb)]       = make_float2(x0.x + x1.x, x0.y + x1.y);
        b[IDX(bb + 256)] = make_float2(x0.x - x1.x, x0.y - x1.y);
    }
    __syncthreads();
    return b;
}

// ISTFT: X=mag*phase -> pack Z=Xe+i*Xo -> IFFT512 -> x[2n]=Re, x[2n+1]=Im -> *syn
// Two frames per block. FIRST: inline threefry random phase (fuses phase-init).
template <bool FIRST>
__global__ __launch_bounds__(256) void k_istft(const float* __restrict__ mag,
                                               const float2* __restrict__ phase,
                                               const float* __restrict__ wins,
                                               float* __restrict__ frames) {
    __shared__ float2 A[2][LDS512];
    __shared__ float2 B[2][LDS512];
    const int t = threadIdx.x, sub = t >> 7, w = t & 127;
    const int bt = blockIdx.x * 2 + sub;
    float2 twr[4][3], ppr[4];
    make_twr(w, twr);
    make_ppr(w, ppr);
    const float*  mg = mag   + (size_t)bt * NFREQ;
    const float2* ph = phase + (size_t)bt * NFREQ;
    auto loadX = [&](int k) -> float2 {
        float m = mg[k];
        float2 p;
        if (FIRST) p = rand_phase(bt * NFREQ + k);
        else       p = ph[k];
        float2 X = make_float2(m * p.x, m * p.y);
        if (k == 0 || k == 512) X.y = 0.f;   // C2R drops imag of DC/Nyquist
        return X;
    };
#pragma unroll
    for (int j = 0; j < 4; ++j) {
        int k = w + 128 * j;
        float2 Xk = loadX(k);
        float2 Xc = loadX(512 - k);
        float ex = 0.5f * (Xk.x + Xc.x), ey = 0.5f * (Xk.y - Xc.y);
        float dx = 0.5f * (Xk.x - Xc.x), dy = 0.5f * (Xk.y + Xc.y);
        float2 c = ppr[j];                        // e^{-i th}; W^{-k} = conj(c)
        float ox = c.x * dx + c.y * dy;
        float oy = c.x * dy - c.y * dx;
        A[sub][IDX(k)] = make_float2(ex - oy, ey + ox);   // Z = Xe + i Xo
    }
    __syncthreads();
    float2* res = fft512<true>(&A[sub][0], &B[sub][0], twr, w);
    float2* out2 = (float2*)(frames + (size_t)bt * NFFT);
    const float2* wn2 = (const float2*)wins;     // wins pre-scaled by 1/512
#pragma unroll
    for (int j = 0; j < 4; ++j) {
        int n = w + 128 * j;
        float2 z = res[IDX(n)];
        float2 wv = wn2[n];
        out2[n] = make_float2(z.x * wv.x, z.y * wv.y);
    }
}

// STFT: z[n]=x[2n]w+i x[2n+1]w -> FFT512 -> unpack X[k] -> phase normalize
__global__ __launch_bounds__(256) void k_stft(const float* __restrict__ sig,
                                              const float* __restrict__ winf,
                                              float2* __restrict__ phase) {
    __shared__ float2 A[2][LDS512];
    __shared__ float2 B[2][LDS512];
    const int t = threadIdx.x, sub = t >> 7, w = t & 127;
    const int bt = blockIdx.x * 2 + sub;
    const int b = bt / NT, tt = bt - b * NT;
    const float2* x2 = (const float2*)(sig + (size_t)b * SIGL + (size_t)tt * HOP);
    const float2* wf2 = (const float2*)winf;
    float2 twr[4][3], ppr[4];
    make_twr(w, twr);
    make_ppr(w, ppr);
#pragma unroll
    for (int j = 0; j < 4; ++j) {
        int n = w + 128 * j;
        float2 v = x2[n];
        float2 wv = wf2[n];
        A[sub][IDX(n)] = make_float2(v.x * wv.x, v.y * wv.y);
    }
    __syncthreads();
    float2* res = fft512<false>(&A[sub][0], &B[sub][0], twr, w);
    float2* out = phase + (size_t)bt * NFREQ;
#pragma unroll
    for (int j = 0; j < 5; ++j) {
        int k = w + 128 * j;
        if (k > 512) break;
        float2 X;
        if (k == 0 || k == 512) {
            float2 z0 = res[IDX(0)];
            X = make_float2((k == 0) ? (z0.x + z0.y) : (z0.x - z0.y), 0.f);
        } else {
            float2 Zk = res[IDX(k)];
            float2 Zc = res[IDX(512 - k)];
            float ex = 0.5f * (Zk.x + Zc.x), ey = 0.5f * (Zk.y - Zc.y);
            float dx = 0.5f * (Zk.x - Zc.x), dy = 0.5f * (Zk.y + Zc.y);
            float ox = dy, oy = -dx;              // O = -i*d
            float2 c = ppr[j];                     // W^{+k} in e^{-i} convention
            X = make_float2(ex + c.x * ox - c.y * oy, ey + c.x * oy + c.y * ox);
        }
        float aab = sqrtf(X.x * X.x + X.y * X.y);
        float iv = 1.0f / fmaxf(1e-10f, aab);
        out[k] = make_float2(X.x * iv, X.y * iv);
    }
}

// overlap-add (gather): sig[b][l] = sum_t frames[b*NT+t][l-256t]
__global__ void k_ola(const float* __restrict__ frames, float* __restrict__ sig) {
    int idx = blockIdx.x * blockDim.x + threadIdx.x;
    if (idx >= NB * SIGL) return;
    int b = idx / SIGL, l = idx - b * SIGL;
    int tmax = min(NT - 1, l >> 8);
    int tmin = (l >= WINL) ? ((l - (WINL - HOP)) >> 8) : 0;
    float s = 0.f;
    for (int t = tmin; t <= tmax; ++t)
        s += frames[((size_t)(b * NT + t)) * NFFT + (l - (t << 8))];
    sig[idx] = s;
}

// ---------------- launcher ----------------
extern "C" void kernel_launch(void* const* d_in, const int* in_sizes, int n_in,
                              void* d_out, int out_size, void* d_ws, size_t ws_size,
                              hipStream_t stream) {
    const float* mel    = (const float*)d_in[0];
    const float* basis  = (const float*)d_in[1];
    const float* smean  = (const float*)d_in[2];
    const float* sscale = (const float*)d_in[3];

    char* ws = (char*)d_ws;
    double* G      = (double*)(ws + OFF_G);
    double* Ginv   = (double*)(ws + OFF_GINV);
    float*  ivT    = (float*) (ws + OFF_INVMEL);
    float*  winf   = (float*) (ws + OFF_WINF);
    float*  wins   = (float*) (ws + OFF_WINS);
    float*  mag    = (float*) (ws + OFF_MAG);
    float2* phase  = (float2*)(ws + OFF_PH);
    float*  frames = (float*) (ws + OFF_FR);
    float*  sig    = (float*) (ws + OFF_SIG);
    float*  outp   = (float*)d_out;

    k_windows<<<1, 256, 0, stream>>>(winf, wins);
    k_gram<<<80, 256, 0, stream>>>(basis, G);
    k_gjinv<<<1, 256, 0, stream>>>(G, Ginv);
    k_invmel<<<(NFREQ * NMEL + 255) / 256, 256, 0, stream>>>(basis, Ginv, ivT);
    k_mag<<<NFRM / MAGROWS, 256, 0, stream>>>(mel, smean, sscale, ivT, mag);

    // iteration 0: phase-init fused into first ISTFT
    k_istft<true><<<NFRM / 2, 256, 0, stream>>>(mag, phase, wins, frames);
    k_ola<<<(NB * SIGL + 255) / 256, 256, 0, stream>>>(frames, sig);
    k_stft<<<NFRM / 2, 256, 0, stream>>>(sig, winf, phase);
    for (int it = 1; it < NITER; ++it) {
        k_istft<false><<<NFRM / 2, 256, 0, stream>>>(mag, phase, wins, frames);
        k_ola<<<(NB * SIGL + 255) / 256, 256, 0, stream>>>(frames, sig);
        k_stft<<<NFRM / 2, 256, 0, stream>>>(sig, winf, phase);
    }
    k_istft<false><<<NFRM / 2, 256, 0, stream>>>(mag, phase, wins, frames);
    k_ola<<<(NB * SIGL + 255) / 256, 256, 0, stream>>>(frames, outp);
}